// Round 1
// 249.762 us; speedup vs baseline: 1.0427x; 1.0427x over previous
//
#include <hip/hip_runtime.h>
#include <hip/hip_bf16.h>

#define NODES 50000
#define EDGES 800000
#define FEAT 128
#define HID 64
#define NCLS 10
#define NGRAPH 512
#define ETOT (EDGES + NODES)
#define NEG_SLOPE 0.2f
#define BN_EPS 1e-5f
#define NT_TILES ((NODES + 63) / 64)  // 782
#define NBINS 98        // bins of 512 nodes: 98*512 = 50176 >= NODES
#define BTILE 8192      // edges per binning block
#define BBLK ((ETOT + BTILE - 1) / BTILE)  // 104
#define BIN_CAP 14336   // max edges/bin (mean ~8700, sigma ~90 -> 62 sigma)
#define TBLK 512        // transform blocks inside k_front
#define EDGE_WAVES 8192 // k_edge waves: 2048 blocks x 4 waves, ~6 nodes/wave

typedef __attribute__((ext_vector_type(8))) short short8;
typedef __attribute__((ext_vector_type(4))) float f32x4;
typedef __attribute__((ext_vector_type(2))) float f32x2;
typedef __attribute__((ext_vector_type(4))) unsigned int u32x4;

// f32 -> bf16 (round-to-nearest-even), result as raw short
__device__ __forceinline__ short f2b(float v) {
  unsigned int u = __float_as_uint(v);
  return (short)((u + 0x7FFFu + ((u >> 16) & 1u)) >> 16);
}
// bf16 (raw short) -> f32
__device__ __forceinline__ float b2f(short s) {
  return __uint_as_float(((unsigned int)(unsigned short)s) << 16);
}

// ---- transform body: MFMA, LDS-staged A + W (R12 structure, f32 weights
// staged coalesced in-kernel; R13: callable from the fused front kernel) ----

__device__ __forceinline__ void transform_body(
    char* smem, int bid, const void* __restrict__ A, int a_bf16, int K,
    const float* __restrict__ Wl, const float* __restrict__ Wr,
    short* __restrict__ xl, short* __restrict__ xr) {
  short* s_a = (short*)smem;            // [64][K+8] bf16
  char* dyn2 = smem + 64 * (K + 8) * 2;
  short* s_w = (short*)dyn2;            // prologue: [128][K+8] bf16
  float* s_out = (float*)dyn2;          // steady-state: [8][16][68] f32
  const int pitch = K + 8;
  int tid = threadIdx.x;
  int w = tid >> 6, lane = tid & 63;
  int n16 = lane & 15, quad = lane >> 4;
  int half = w & 1, chunk = w >> 1;
  short* outp = half ? xr : xl;
  float* s_ow = s_out + w * 16 * 68;
  int ktn = K >> 5;
  int kq = K >> 2, ksh = (K == 128) ? 5 : 4;

  // stage weights coalesced: f32 float4 reads -> bf16 short4 -> padded LDS
  for (int i = tid; i < 128 * kq; i += 512) {
    int r = i / kq, c = i - r * kq;
    const float* src = (r < 64) ? Wl : Wr;
    float4 v = *((const float4*)(src + (r & 63) * K) + c);
    short4 bb;
    bb.x = f2b(v.x); bb.y = f2b(v.y); bb.z = f2b(v.z); bb.w = f2b(v.w);
    *(short4*)(s_w + r * pitch + c * 4) = bb;
  }
  __syncthreads();
  short8 bfrag[4][4];
  for (int t = 0; t < 4; ++t)
    for (int kt = 0; kt < ktn; ++kt)
      bfrag[t][kt] = *(const short8*)(s_w + (half * 64 + t * 16 + n16) * pitch + kt * 32 + quad * 8);

  for (int nt = bid; nt < NT_TILES; nt += TBLK) {
    int n0 = nt * 64;
    __syncthreads();
    if (a_bf16) {  // bf16 input: raw 16B copies
      int ku = K >> 3;
      for (int i = tid; i < 64 * ku; i += 512) {
        int row = i / ku, c = i - row * ku;
        int grow = n0 + row;
        short8 v = (short8){0, 0, 0, 0, 0, 0, 0, 0};
        if (grow < NODES) v = ((const short8*)((const short*)A + (size_t)grow * K))[c];
        *(short8*)(s_a + row * pitch + c * 8) = v;
      }
    } else {  // f32 input -> bf16
      for (int i = tid; i < (64 << ksh); i += 512) {
        int row = i >> ksh, kc = i & (kq - 1);
        int grow = n0 + row;
        float4 v = (grow < NODES) ? *((const float4*)((const float*)A + (size_t)grow * K) + kc)
                                  : make_float4(0.f, 0.f, 0.f, 0.f);
        short4 bb;
        bb.x = f2b(v.x); bb.y = f2b(v.y); bb.z = f2b(v.z); bb.w = f2b(v.w);
        *(short4*)(s_a + row * pitch + kc * 4) = bb;
      }
    }
    __syncthreads();
    f32x4 acc[4];
#pragma unroll
    for (int t = 0; t < 4; ++t) acc[t] = (f32x4){0.f, 0.f, 0.f, 0.f};
    const short* arow = s_a + (chunk * 16 + n16) * pitch + quad * 8;
    for (int kt = 0; kt < ktn; ++kt) {
      short8 af = *(const short8*)(arow + kt * 32);
#pragma unroll
      for (int t = 0; t < 4; ++t)
        acc[t] = __builtin_amdgcn_mfma_f32_16x16x32_bf16(af, bfrag[t][kt], acc[t], 0, 0, 0);
    }
#pragma unroll
    for (int t = 0; t < 4; ++t)
#pragma unroll
      for (int r = 0; r < 4; ++r)
        s_ow[(quad * 4 + r) * 68 + t * 16 + n16] = acc[t][r];
#pragma unroll
    for (int it = 0; it < 4; ++it) {
      int i = it * 64 + lane;
      int row = i >> 4, c4 = i & 15;
      int grow = n0 + chunk * 16 + row;
      if (grow < NODES) {
        float4 v = *(const float4*)(s_ow + row * 68 + c4 * 4);
        short4 bb;
        bb.x = f2b(v.x); bb.y = f2b(v.y); bb.z = f2b(v.z); bb.w = f2b(v.w);
        *(short4*)(outp + (size_t)grow * HID + c4 * 4) = bb;
      }
    }
  }
}

// ---- edge binning body (R13: fixed-capacity bins, no pre-scan) ----

__device__ __forceinline__ void binscatter_body(
    char* smem, int bid, const int* __restrict__ ei,
    int* __restrict__ binCursor, unsigned int* __restrict__ binned) {
  int* h = (int*)smem;
  int* b0 = h + NBINS;
  int tid = threadIdx.x;
  for (int i = tid; i < NBINS; i += 512) h[i] = 0;
  __syncthreads();
  int base = bid * BTILE;
  for (int k = 0; k < BTILE; k += 512) {  // pass 1: local per-bin counts
    int i = base + k + tid;
    if (i < ETOT) {
      int d = (i < EDGES) ? ei[EDGES + i] : (i - EDGES);  // self-loop for i>=E
      atomicAdd(&h[d >> 9], 1);
    }
  }
  __syncthreads();
  for (int i = tid; i < NBINS; i += 512) {
    b0[i] = h[i] ? atomicAdd(&binCursor[i], h[i]) : 0;
    h[i] = 0;
  }
  __syncthreads();
  for (int k = 0; k < BTILE; k += 512) {  // pass 2: clustered writes
    int i = base + k + tid;
    if (i < ETOT) {
      int s, d;
      if (i < EDGES) { s = ei[i]; d = ei[EDGES + i]; }
      else { s = d = i - EDGES; }
      int bin = d >> 9;
      int r = atomicAdd(&h[bin], 1);
      binned[(size_t)bin * BIN_CAP + b0[bin] + r] =
          (unsigned int)s | ((unsigned int)(d & 511) << 16);
    }
  }
}

// ---- fused front: transform L1 (blocks 0..511) || edge binning (512..615) ----

__global__ void __launch_bounds__(512) k_front(
    const float* __restrict__ x, const float* __restrict__ Wl1,
    const float* __restrict__ Wr1, short* __restrict__ xl, short* __restrict__ xr,
    const int* __restrict__ ei, int* __restrict__ binCursor,
    unsigned int* __restrict__ binned) {
  extern __shared__ char smem[];
  if (blockIdx.x < TBLK)
    transform_body(smem, blockIdx.x, x, 0, FEAT, Wl1, Wr1, xl, xr);
  else
    binscatter_body(smem, blockIdx.x - TBLK, ei, binCursor, binned);
}

__global__ void __launch_bounds__(512) k_transform2(
    const short* __restrict__ h, const float* __restrict__ Wl2,
    const float* __restrict__ Wr2, short* __restrict__ xl, short* __restrict__ xr) {
  extern __shared__ char smem[];
  transform_body(smem, blockIdx.x, h, 1, HID, Wl2, Wr2, xl, xr);
}

// ---- per-bin CSR build (blocks 0..97) + graph bounds (block 98) ----

__global__ void __launch_bounds__(512) k_csr(
    const int* __restrict__ binCursor, const unsigned int* __restrict__ binned,
    int* __restrict__ rowstart, unsigned short* __restrict__ rowcnt,
    unsigned short* __restrict__ srcs, const int* __restrict__ batch,
    int* __restrict__ gstart) {
  __shared__ int h[512], sc[512], cur[512];
  __shared__ unsigned short sl[BIN_CAP];
  int b = blockIdx.x, t = threadIdx.x;
  if (b == NBINS) {  // graph bounds: batch sorted -> contiguous ranges
    for (int g = t; g <= NGRAPH; g += 512) {
      int lo = 0, hi = NODES;
      while (lo < hi) { int mid = (lo + hi) >> 1; if (batch[mid] < g) lo = mid + 1; else hi = mid; }
      gstart[g] = lo;
    }
    return;
  }
  size_t e0 = (size_t)b * BIN_CAP;
  int cnt = binCursor[b];
  int n0 = b << 9;
  h[t] = 0;
  __syncthreads();
  for (int i = t; i < cnt; i += 512)
    atomicAdd(&h[binned[e0 + i] >> 16], 1);
  __syncthreads();
  sc[t] = h[t];
  __syncthreads();
  for (int off = 1; off < 512; off <<= 1) {  // inclusive scan
    int v = (t >= off) ? sc[t - off] : 0;
    __syncthreads();
    sc[t] += v;
    __syncthreads();
  }
  int excl = sc[t] - h[t];
  cur[t] = excl;
  int node = n0 + t;
  if (node < NODES) {
    rowstart[node] = (int)e0 + excl;
    rowcnt[node] = (unsigned short)h[t];
  }
  __syncthreads();
  for (int i = t; i < cnt; i += 512) {  // scatter within LDS
    unsigned int p = binned[e0 + i];
    int slot = atomicAdd(&cur[p >> 16], 1);
    sl[slot] = (unsigned short)(p & 0xFFFFu);
  }
  __syncthreads();
  for (int i = t; i < cnt; i += 512)  // coalesced write-out
    srcs[e0 + i] = sl[i];
}

// ---- GATv2 edge pass: grid-stride waves, cross-node pipeline, 8 edges/iter,
// 1-deep gather prefetch. R14: feature math on f32x2 -> v_pk_{add,mul,max,fma}_f32
// packed VALU (halves the per-feature op count); leaky as max(v, 0.2v). ----

__global__ void __launch_bounds__(256) k_edge(
    const int* __restrict__ rowstart, const unsigned short* __restrict__ rowcnt,
    const unsigned short* __restrict__ srcs,
    const short* __restrict__ xlb, const short* __restrict__ xrb,
    const float* __restrict__ att, const float* __restrict__ bias,
    short* __restrict__ outb, int do_relu) {
  int wv = blockIdx.x * 4 + (threadIdx.x >> 6);
  int lane = threadIdx.x & 63;
  int fg = lane & 7;      // feature group of 8
  int eslot = lane >> 3;  // edge slot 0..7
  f32x2 at2[4], bb2[4];
  {
    float4 a0 = *(const float4*)(att + fg * 8);
    float4 a1 = *(const float4*)(att + fg * 8 + 4);
    at2[0] = (f32x2){a0.x, a0.y}; at2[1] = (f32x2){a0.z, a0.w};
    at2[2] = (f32x2){a1.x, a1.y}; at2[3] = (f32x2){a1.z, a1.w};
    float4 b0 = *(const float4*)(bias + fg * 8);
    float4 b1 = *(const float4*)(bias + fg * 8 + 4);
    bb2[0] = (f32x2){b0.x, b0.y}; bb2[1] = (f32x2){b0.z, b0.w};
    bb2[2] = (f32x2){b1.x, b1.y}; bb2[3] = (f32x2){b1.z, b1.w};
  }
  int wid = wv;
  if (wid >= NODES) return;
  int nbeg = rowstart[wid];
  int ncnt = rowcnt[wid];
  short8 nxr = *(const short8*)(xrb + (size_t)wid * HID + fg * 8);
  while (true) {
    int beg = nbeg, end = nbeg + ncnt;
    short8 xrs = nxr;
    int nwid = wid + EDGE_WAVES;
    if (nwid < NODES) {  // prefetch next node's metadata, consumed next iter
      nbeg = rowstart[nwid];
      ncnt = rowcnt[nwid];
      nxr = *(const short8*)(xrb + (size_t)nwid * HID + fg * 8);
    }
    f32x2 xr2[4], acc2[4];
    u32x4 ur = *(u32x4*)&xrs;
#pragma unroll
    for (int q = 0; q < 4; ++q) {
      xr2[q] = (f32x2){__uint_as_float(ur[q] << 16),
                       __uint_as_float(ur[q] & 0xFFFF0000u)};
      acc2[q] = (f32x2){0.f, 0.f};
    }
    float denom = 0.f;
    for (int base = beg; base < end; base += 64) {
      int cnt = end - base; if (cnt > 64) cnt = 64;
      int myidx = (lane < cnt) ? (int)srcs[base + lane] : 0;
      int j0 = eslot;
      int sP = __shfl(myidx, (j0 < cnt) ? j0 : 0, 64);
      short8 xs = *(const short8*)(xlb + (size_t)sP * HID + fg * 8);
      for (int j = 0; j < cnt; j += 8) {
        bool valid = (j + eslot) < cnt;
        short8 cur = xs;
        if (j + 8 < cnt) {  // prefetch next gather before the shfl/exp chain
          int jn = j + 8 + eslot;
          int sn = __shfl(myidx, (jn < cnt) ? jn : 0, 64);
          xs = *(const short8*)(xlb + (size_t)sn * HID + fg * 8);
        }
        u32x4 uc = *(u32x4*)&cur;
        f32x2 c2[4];
        f32x2 dp = {0.f, 0.f};
#pragma unroll
        for (int q = 0; q < 4; ++q) {
          c2[q] = (f32x2){__uint_as_float(uc[q] << 16),
                          __uint_as_float(uc[q] & 0xFFFF0000u)};
          f32x2 v = c2[q] + xr2[q];
          v = __builtin_elementwise_max(v, v * NEG_SLOPE);  // leaky, 2 pk-ops
          dp += v * at2[q];                                 // pk_fma
        }
        float part = dp[0] + dp[1];
        part += __shfl_xor(part, 1, 64);
        part += __shfl_xor(part, 2, 64);
        part += __shfl_xor(part, 4, 64);
        float p = valid ? __expf(part) : 0.f;
        denom += p;
        f32x2 pv = {p, p};
#pragma unroll
        for (int q = 0; q < 4; ++q) acc2[q] += pv * c2[q];  // pk_fma
      }
    }
    denom += __shfl_xor(denom, 8, 64);
    denom += __shfl_xor(denom, 16, 64);
    denom += __shfl_xor(denom, 32, 64);
#pragma unroll
    for (int q = 0; q < 4; ++q) {
      acc2[q][0] += __shfl_xor(acc2[q][0], 8, 64);
      acc2[q][0] += __shfl_xor(acc2[q][0], 16, 64);
      acc2[q][0] += __shfl_xor(acc2[q][0], 32, 64);
      acc2[q][1] += __shfl_xor(acc2[q][1], 8, 64);
      acc2[q][1] += __shfl_xor(acc2[q][1], 16, 64);
      acc2[q][1] += __shfl_xor(acc2[q][1], 32, 64);
    }
    if (eslot == 0) {
      float inv = 1.f / denom;
      short8 o;
#pragma unroll
      for (int q = 0; q < 4; ++q) {
        float o0 = acc2[q][0] * inv + bb2[q][0];
        float o1 = acc2[q][1] * inv + bb2[q][1];
        if (do_relu) { o0 = fmaxf(o0, 0.f); o1 = fmaxf(o1, 0.f); }
        o[2 * q] = f2b(o0);
        o[2 * q + 1] = f2b(o1);
      }
      *(short8*)(outb + (size_t)wid * HID + fg * 8) = o;
    }
    if (nwid >= NODES) break;
    wid = nwid;
  }
}

// ---- global mean pool + fused head1 (R14): after the wave-level pool
// reduce, each wave holds its graph's pooled vector -> compute
// z = pooled @ W3^T + b3 in-kernel (one output feature per lane). ----

__global__ void __launch_bounds__(256) k_pool(
    const short* __restrict__ h, const int* __restrict__ gstart,
    const float* __restrict__ W3, const float* __restrict__ b3,
    float* __restrict__ z) {
  __shared__ float s_pool[4 * 64];
  int w = threadIdx.x >> 6;            // wave 0..3
  int g = blockIdx.x * 4 + w;          // grid is exactly NGRAPH/4 -> g < NGRAPH
  int lane = threadIdx.x & 63;
  int fg = lane & 7, ns = lane >> 3;
  int beg = gstart[g], end = gstart[g + 1];
  float acc[8] = {0.f, 0.f, 0.f, 0.f, 0.f, 0.f, 0.f, 0.f};
  for (int n = beg + ns; n < end; n += 8) {
    short8 v = *(const short8*)(h + (size_t)n * HID + fg * 8);
#pragma unroll
    for (int q = 0; q < 8; ++q) acc[q] += b2f(v[q]);
  }
#pragma unroll
  for (int q = 0; q < 8; ++q) {
    acc[q] += __shfl_xor(acc[q], 8, 64);
    acc[q] += __shfl_xor(acc[q], 16, 64);
    acc[q] += __shfl_xor(acc[q], 32, 64);
  }
  if (ns == 0) {
    float inv = 1.f / fmaxf((float)(end - beg), 1.f);
#pragma unroll
    for (int q = 0; q < 8; ++q) s_pool[w * 64 + fg * 8 + q] = acc[q] * inv;
  }
  __syncthreads();
  // head1: lane computes one output feature f = lane for graph g
  float zacc = b3[lane];
  const float* w3r = W3 + lane * HID;
  const float* pg = s_pool + w * 64;
#pragma unroll 4
  for (int k = 0; k < HID; k += 4) {
    float4 wv = *(const float4*)(w3r + k);
    zacc += pg[k] * wv.x + pg[k + 1] * wv.y + pg[k + 2] * wv.z + pg[k + 3] * wv.w;
  }
  z[g * HID + lane] = zacc;
}

// ---- fused BN stats + head3 (R14): one block, 512 threads.
// Phase A: segmented column stats (8 segs x 64 feats) -> LDS tree -> scale/shift.
// Phase B: one graph per thread: BN affine + ReLU + W4 + log_softmax. ----

__global__ void __launch_bounds__(512) k_tail(
    const float* __restrict__ z, const float* __restrict__ gamma,
    const float* __restrict__ beta, const float* __restrict__ W4,
    const float* __restrict__ b4, float* __restrict__ out) {
  __shared__ float s_p1[8][64];
  __shared__ float s_p2[8][64];
  __shared__ float s_sc[64], s_sh[64];
  __shared__ float s_w4[NCLS * HID];
  int t = threadIdx.x;
  int f = t & 63, seg = t >> 6;
  float s = 0.f, s2 = 0.f;
  for (int g = seg * 64; g < seg * 64 + 64; ++g) {
    float v = z[g * HID + f];
    s += v; s2 += v * v;
  }
  s_p1[seg][f] = s;
  s_p2[seg][f] = s2;
  for (int i = t; i < NCLS * HID; i += 512) s_w4[i] = W4[i];
  __syncthreads();
  if (t < 64) {
    float ss = 0.f, ss2 = 0.f;
#pragma unroll
    for (int k = 0; k < 8; ++k) { ss += s_p1[k][t]; ss2 += s_p2[k][t]; }
    float mu = ss / NGRAPH;
    float var = ss2 / NGRAPH - mu * mu;  // biased var (training-mode BN)
    float rstd = rsqrtf(var + BN_EPS);
    float sc = gamma[t] * rstd;
    s_sc[t] = sc;
    s_sh[t] = beta[t] - mu * sc;
  }
  __syncthreads();
  // head3: thread t = graph t (NGRAPH == 512 == blockDim)
  float acc[NCLS];
#pragma unroll
  for (int c = 0; c < NCLS; ++c) acc[c] = b4[c];
  const float* zr = z + t * HID;
  for (int f0 = 0; f0 < HID; f0 += 4) {
    float4 zv = *(const float4*)(zr + f0);
    float zn0 = fmaxf(zv.x * s_sc[f0] + s_sh[f0], 0.f);
    float zn1 = fmaxf(zv.y * s_sc[f0 + 1] + s_sh[f0 + 1], 0.f);
    float zn2 = fmaxf(zv.z * s_sc[f0 + 2] + s_sh[f0 + 2], 0.f);
    float zn3 = fmaxf(zv.w * s_sc[f0 + 3] + s_sh[f0 + 3], 0.f);
#pragma unroll
    for (int c = 0; c < NCLS; ++c)
      acc[c] += zn0 * s_w4[c * HID + f0] + zn1 * s_w4[c * HID + f0 + 1] +
                zn2 * s_w4[c * HID + f0 + 2] + zn3 * s_w4[c * HID + f0 + 3];
  }
  float m = acc[0];
#pragma unroll
  for (int c = 1; c < NCLS; ++c) m = fmaxf(m, acc[c]);
  float sum = 0.f;
#pragma unroll
  for (int c = 0; c < NCLS; ++c) sum += __expf(acc[c] - m);
  float lse = m + __logf(sum);
#pragma unroll
  for (int c = 0; c < NCLS; ++c) out[t * NCLS + c] = acc[c] - lse;
}

extern "C" void kernel_launch(void* const* d_in, const int* in_sizes, int n_in,
                              void* d_out, int out_size, void* d_ws, size_t ws_size,
                              hipStream_t stream) {
  (void)in_sizes; (void)n_in; (void)out_size; (void)ws_size;
  const float* x     = (const float*)d_in[0];
  const int*   ei    = (const int*)d_in[1];
  const int*   batch = (const int*)d_in[2];
  const float* Wl1   = (const float*)d_in[3];
  const float* Wr1   = (const float*)d_in[4];
  const float* att1  = (const float*)d_in[5];
  const float* b1    = (const float*)d_in[6];
  const float* Wl2   = (const float*)d_in[7];
  const float* Wr2   = (const float*)d_in[8];
  const float* att2  = (const float*)d_in[9];
  const float* b2    = (const float*)d_in[10];
  const float* W3    = (const float*)d_in[11];
  const float* b3    = (const float*)d_in[12];
  const float* gamma = (const float*)d_in[13];
  const float* beta  = (const float*)d_in[14];
  const float* W4    = (const float*)d_in[15];
  const float* b4    = (const float*)d_in[16];
  float* out = (float*)d_out;

  char* ws = (char*)d_ws;
  size_t off = 0;
  auto alloc = [&](size_t bytes) -> char* {
    char* p = ws + off;
    off += (bytes + 255) & ~(size_t)255;
    return p;
  };
  int*      binCursor = (int*)alloc((size_t)NBINS * 4);
  unsigned int*   binned = (unsigned int*)alloc((size_t)NBINS * BIN_CAP * 4);
  unsigned short* srcs   = (unsigned short*)alloc((size_t)NBINS * BIN_CAP * 2);
  int*      rowstart  = (int*)alloc((size_t)NODES * 4);
  unsigned short* rowcnt = (unsigned short*)alloc((size_t)NODES * 2);
  int*      gstart    = (int*)alloc((size_t)(NGRAPH + 1) * 4);
  short*    bufA      = (short*)alloc((size_t)NODES * HID * 2);  // xl bf16
  short*    bufB      = (short*)alloc((size_t)NODES * HID * 2);  // xr bf16
  short*    bufC      = (short*)alloc((size_t)NODES * HID * 2);  // h  bf16
  float*    z         = (float*)alloc((size_t)NGRAPH * HID * 4);

  // LDS bytes: A-tile bf16 64*(K+8)*2 + W/C region 34816 (=128*(K+8)*2 @K=128)
  int lds1 = 64 * (FEAT + 8) * 2 + 34816;  // 52224
  int lds2 = 64 * (HID + 8) * 2 + 34816;   // 44032

  hipMemsetAsync(binCursor, 0, (size_t)NBINS * 4, stream);
  // Fused: transform L1 (512 blocks) || edge binning (104 blocks)
  k_front<<<TBLK + BBLK, 512, lds1, stream>>>(x, Wl1, Wr1, bufA, bufB, ei, binCursor, binned);
  // Per-bin CSR (98 blocks) + graph bounds (block 98)
  k_csr<<<NBINS + 1, 512, 0, stream>>>(binCursor, binned, rowstart, rowcnt, srcs, batch, gstart);
  // Layer 1 edge pass
  k_edge<<<EDGE_WAVES / 4, 256, 0, stream>>>(rowstart, rowcnt, srcs, bufA, bufB, att1, b1, bufC, 1);
  // Layer 2
  k_transform2<<<TBLK, 512, lds2, stream>>>(bufC, Wl2, Wr2, bufA, bufB);
  k_edge<<<EDGE_WAVES / 4, 256, 0, stream>>>(rowstart, rowcnt, srcs, bufA, bufB, att2, b2, bufC, 0);
  // Pool + fused head1
  k_pool<<<NGRAPH / 4, 256, 0, stream>>>(bufC, gstart, W3, b3, z);
  // Fused BN stats + head3
  k_tail<<<1, 512, 0, stream>>>(z, gamma, beta, W4, b4, out);
}